// Round 6
// baseline (1500.601 us; speedup 1.0000x reference)
//
#include <hip/hip_runtime.h>
#include <hip/hip_bf16.h>
#include <cstdint>
#include <cstddef>

// Qwen3 MoE layer: T=2048 tokens, H=1024 hidden, E=64 experts, I=768, top-K=8
#define T_TOK 2048
#define H_DIM 1024
#define E_NUM 64
#define I_DIM 768
#define K_TOP 8
#define BM 384  // one tile covers any expert (ne ~ 256 +/- 16; P(ne>384) ~ 1e-15)

typedef __attribute__((ext_vector_type(8))) __bf16 bf16x8;
typedef __attribute__((ext_vector_type(4))) __bf16 bf16x4;
typedef __attribute__((ext_vector_type(8))) unsigned short u16x8;
typedef __attribute__((ext_vector_type(4))) float f32x4;
typedef unsigned short ushort_t;

__device__ __forceinline__ unsigned short f2bf(float f) {
  uint32_t u = __builtin_bit_cast(uint32_t, f);
  u += 0x7fffu + ((u >> 16) & 1u);
  return (unsigned short)(u >> 16);
}

__device__ __forceinline__ bf16x8 cvt8b(f32x4 a, f32x4 b) {
  bf16x8 r;
  r[0] = (__bf16)a[0]; r[1] = (__bf16)a[1]; r[2] = (__bf16)a[2]; r[3] = (__bf16)a[3];
  r[4] = (__bf16)b[0]; r[5] = (__bf16)b[1]; r[6] = (__bf16)b[2]; r[7] = (__bf16)b[3];
  return r;
}

__device__ __forceinline__ bf16x4 cvt4b(f32x4 a) {
  bf16x4 r;
  r[0] = (__bf16)a[0]; r[1] = (__bf16)a[1]; r[2] = (__bf16)a[2]; r[3] = (__bf16)a[3];
  return r;
}

// async 16B global -> LDS; dest = wave-uniform base (HW adds lane*16)
__device__ __forceinline__ void async16(void* l, const void* g) {
  __builtin_amdgcn_global_load_lds(
      (const __attribute__((address_space(1))) unsigned int*)g,
      (__attribute__((address_space(3))) unsigned int*)l, 16, 0, 0);
}

// ---------------- x f32 -> bf16 pre-cast ----------------
__global__ __launch_bounds__(256) void xcast_kernel(const float* __restrict__ x,
                                                    ushort_t* __restrict__ xb) {
  int i = blockIdx.x * 256 + threadIdx.x;
  const f32x4* s = (const f32x4*)(x + (size_t)i * 8);
  *(bf16x8*)(xb + (size_t)i * 8) = cvt8b(s[0], s[1]);
}

// ---------------- router ----------------
__global__ __launch_bounds__(64) void router_kernel(
    const float* __restrict__ x, const float* __restrict__ wr,
    int* __restrict__ topk_id, float* __restrict__ topk_w,
    int* __restrict__ counts) {
  const int t = blockIdx.x;
  const int e = threadIdx.x;
  const float4* xv = (const float4*)(x + (size_t)t * H_DIM);
  const float4* wv = (const float4*)(wr + (size_t)e * H_DIM);
  float acc = 0.f;
#pragma unroll 8
  for (int i = 0; i < H_DIM / 4; ++i) {
    float4 a = xv[i], b = wv[i];
    acc = fmaf(a.x, b.x, acc);
    acc = fmaf(a.y, b.y, acc);
    acc = fmaf(a.z, b.z, acc);
    acc = fmaf(a.w, b.w, acc);
  }
  float m = acc;
  for (int o = 32; o; o >>= 1) m = fmaxf(m, __shfl_xor(m, o));
  float p = __expf(acc - m);
  float s = p;
  for (int o = 32; o; o >>= 1) s += __shfl_xor(s, o);
  p /= s;
  float v = p;
  int sid = 0;
  float sw = 0.f;
  for (int k = 0; k < K_TOP; ++k) {
    float bv = v;
    int bi = e;
    for (int o = 32; o; o >>= 1) {
      float ov = __shfl_xor(bv, o);
      int oi = __shfl_xor(bi, o);
      if (ov > bv || (ov == bv && oi < bi)) { bv = ov; bi = oi; }
    }
    if (e == k) { sid = bi; sw = bv; }
    if (e == bi) v = -1.f;
  }
  float ssum = (e < K_TOP) ? sw : 0.f;
  for (int o = 32; o; o >>= 1) ssum += __shfl_xor(ssum, o);
  if (e < K_TOP) {
    topk_id[t * K_TOP + e] = sid;
    topk_w[t * K_TOP + e] = sw / ssum;
    atomicAdd(&counts[sid], 1);
  }
}

// ---------------- scan + packed tile list (BM=384) ----------------
__global__ void scan_kernel(const int* __restrict__ counts,
                            int* __restrict__ offsets, int* __restrict__ cursor,
                            int* __restrict__ tile_list, int* __restrict__ n_tiles) {
  if (threadIdx.x == 0) {
    int a = 0, n = 0;
    for (int e = 0; e < E_NUM; ++e) {
      offsets[e] = a;
      cursor[e] = a;
      int ne = counts[e];
      a += ne;
      int tl = (ne + BM - 1) / BM;
      if (tl > 2) tl = 2;
      for (int m = 0; m < tl; ++m) tile_list[n++] = (e << 2) | m;
    }
    *n_tiles = n;
  }
}

__global__ __launch_bounds__(256) void build_kernel(
    const int* __restrict__ topk_id, const float* __restrict__ topk_w,
    int* __restrict__ cursor, int* __restrict__ pair_token, float* __restrict__ pair_w) {
  int i = blockIdx.x * 256 + threadIdx.x;
  int t = i >> 3;
  int e = topk_id[i];
  int pos = atomicAdd(&cursor[e], 1);
  pair_token[pos] = t;
  pair_w[pos] = topk_w[i];
}

// bf16 LDS tiles: rows of 32 bf16 (64B = 4 chunks of 16B), chunk slot = c ^ ((row>>1)&3)

// ================= stage 1: h = silu(X Wg^T) * (X Wu^T) =================
// BM=384, BN=64 (G and U), BK=32, 768 thr (12 waves 6Mx2N), 2 blocks/CU.
// All waves: 2 X-DMA/tile. Waves 0-7: +2 W reg-loads (f32->bf16->ds_write).
#define GU_NIT 32
#define GU_TILES 96

__global__ __launch_bounds__(768, 6) void gemm_gu_kernel(
    const ushort_t* __restrict__ xb, const float* __restrict__ wg,
    const float* __restrict__ wu, const int* __restrict__ offsets,
    const int* __restrict__ counts, const int* __restrict__ pair_token,
    const int* __restrict__ tile_list, const int* __restrict__ n_tiles,
    ushort_t* __restrict__ h_buf) {
  int idx = blockIdx.x;
  int tl = idx / 12, nt = idx - tl * 12;
  if (tl >= *n_tiles) return;
  int ent = tile_list[tl];
  int e = ent >> 2, mt = ent & 3;
  int ne = counts[e], off = offsets[e];
  int ib = nt * 64;
  int vr = ne - mt * BM;
  if (vr <= 0) return;
  if (vr > BM) vr = BM;

  __shared__ __align__(16) ushort_t Xs[2][BM * 32];  // 24 KB x2
  __shared__ __align__(16) ushort_t Gs[2][64 * 32];  //  4 KB x2
  __shared__ __align__(16) ushort_t Us[2][64 * 32];  //  4 KB x2
  __shared__ int sTok[BM];

  const int tid = threadIdx.x;
  const int lane = tid & 63;
  const int wid = tid >> 6;  // 0..11
  if (tid < BM) {
    int p = mt * BM + tid;
    sTok[tid] = pair_token[off + (p < ne ? p : ne - 1)];
  }
  __syncthreads();

  // X DMA: 1536 chunks of 16B, 2 per thread; linear LDS dest + inverse-swizzled src
  const ushort_t* xsrc[2];
#pragma unroll
  for (int j = 0; j < 2; ++j) {
    int p = j * 768 + tid;
    int row = p >> 2, c = p & 3;
    xsrc[j] = xb + (size_t)sTok[row] * H_DIM + ((c ^ ((row >> 1) & 3)) << 3);
  }
  // W reg-staging (waves 0-7 only): 1 f32x4 per G and U per tile
  const float* gsrc = wg;
  const float* usrc = wu;
  int wdsti = 0;
  if (wid < 8) {
    int wrow = tid >> 3, wq = tid & 7;  // tid<512 -> wrow 0..63
    size_t ro = ((size_t)e * I_DIM + ib + wrow) * H_DIM + wq * 4;
    gsrc = wg + ro;
    usrc = wu + ro;
    wdsti = wrow * 32 + (((wq >> 1) ^ ((wrow >> 1) & 3)) << 3) + ((wq & 1) << 2);
  }

  const int wrM = wid >> 1, wrN = wid & 1;  // 6M x 2N
  const int lrow = lane & 15, lk = lane >> 4;
  const bool wact = (wrM * 64) < vr;

  f32x4 accG[4][2], accU[4][2];
#pragma unroll
  for (int mi = 0; mi < 4; ++mi)
#pragma unroll
    for (int ni = 0; ni < 2; ++ni) {
      accG[mi][ni] = f32x4{0.f, 0.f, 0.f, 0.f};
      accU[mi][ni] = f32x4{0.f, 0.f, 0.f, 0.f};
    }

  f32x4 g0 = {0, 0, 0, 0}, u0 = {0, 0, 0, 0}, g1 = {0, 0, 0, 0}, u1 = {0, 0, 0, 0};

#define GU_XDMA(B, K0)                                             \
  do {                                                             \
    async16(&Xs[B][(wid * 64) * 8], xsrc[0] + (K0));               \
    async16(&Xs[B][(768 + wid * 64) * 8], xsrc[1] + (K0));         \
  } while (0)

#define GU_WAIT_STEADY                                                      \
  do {                                                                      \
    if (wid < 8) asm volatile("s_waitcnt vmcnt(4)" ::: "memory");           \
    else         asm volatile("s_waitcnt vmcnt(2)" ::: "memory");           \
  } while (0)

#define GU_BODY(B)                                                                       \
  do {                                                                                   \
    if (wact) {                                                                          \
      __builtin_amdgcn_s_setprio(1);                                                     \
      bf16x8 af[4];                                                                      \
      _Pragma("unroll") for (int mi = 0; mi < 4; ++mi) {                                 \
        int r = wrM * 64 + mi * 16 + lrow;                                               \
        af[mi] = __builtin_bit_cast(                                                     \
            bf16x8, *(const u16x8*)&Xs[B][r * 32 + ((lk ^ ((r >> 1) & 3)) << 3)]);       \
      }                                                                                  \
      _Pragma("unroll") for (int ni = 0; ni < 2; ++ni) {                                 \
        int br = wrN * 32 + ni * 16 + lrow;                                              \
        int ci = br * 32 + ((lk ^ ((br >> 1) & 3)) << 3);                                \
        bf16x8 bg = __builtin_bit_cast(bf16x8, *(const u16x8*)&Gs[B][ci]);               \
        bf16x8 bu = __builtin_bit_cast(bf16x8, *(const u16x8*)&Us[B][ci]);               \
        _Pragma("unroll") for (int mi = 0; mi < 4; ++mi) {                               \
          accG[mi][ni] =                                                                 \
              __builtin_amdgcn_mfma_f32_16x16x32_bf16(af[mi], bg, accG[mi][ni], 0, 0, 0);\
          accU[mi][ni] =                                                                 \
              __builtin_amdgcn_mfma_f32_16x16x32_bf16(af[mi], bu, accU[mi][ni], 0, 0, 0);\
        }                                                                                \
      }                                                                                  \
      __builtin_amdgcn_s_setprio(0);                                                     \
    }                                                                                    \
  } while (0)

#define GU_ITER(K, B, GW, UW, GI, UI)                                    \
  do {                                                                   \
    if ((K) + 2 < GU_NIT && wid < 8) {                                   \
      GI = *(const f32x4*)(gsrc + ((K) + 2) * 32);                       \
      UI = *(const f32x4*)(usrc + ((K) + 2) * 32);                       \
    }                                                                    \
    GU_BODY(B);                                                          \
    asm volatile("s_waitcnt lgkmcnt(0)" ::: "memory");                   \
    __builtin_amdgcn_s_barrier();                                        \
    __builtin_amdgcn_sched_barrier(0);                                   \
    if ((K) + 2 < GU_NIT) {                                              \
      GU_XDMA(B, ((K) + 2) * 32);                                        \
      GU_WAIT_STEADY;                                                    \
    } else {                                                             \
      asm volatile("s_waitcnt vmcnt(0)" ::: "memory");                   \
    }                                                                    \
    __builtin_amdgcn_sched_barrier(0);                                   \
    if ((K) + 1 < GU_NIT && wid < 8) {                                   \
      *(bf16x4*)&Gs[(B) ^ 1][wdsti] = cvt4b(GW);                         \
      *(bf16x4*)&Us[(B) ^ 1][wdsti] = cvt4b(UW);                         \
    }                                                                    \
    asm volatile("s_waitcnt lgkmcnt(0)" ::: "memory");                   \
    __builtin_amdgcn_s_barrier();                                        \
    __builtin_amdgcn_sched_barrier(0);                                   \
  } while (0)

  // prologue: per-wave FIFO (w<8): [g0,u0,X0,X0, g1,u1,X1,X1] -> vmcnt(4) = tile0 done
  if (wid < 8) {
    g0 = *(const f32x4*)(gsrc);
    u0 = *(const f32x4*)(usrc);
  }
  GU_XDMA(0, 0);
  if (wid < 8) {
    g1 = *(const f32x4*)(gsrc + 32);
    u1 = *(const f32x4*)(usrc + 32);
  }
  GU_XDMA(1, 32);
  GU_WAIT_STEADY;
  __builtin_amdgcn_sched_barrier(0);
  if (wid < 8) {
    *(bf16x4*)&Gs[0][wdsti] = cvt4b(g0);
    *(bf16x4*)&Us[0][wdsti] = cvt4b(u0);
  }
  asm volatile("s_waitcnt lgkmcnt(0)" ::: "memory");
  __builtin_amdgcn_s_barrier();
  __builtin_amdgcn_sched_barrier(0);

  for (int kk = 0; kk < GU_NIT; kk += 2) {
    GU_ITER(kk, 0, g1, u1, g0, u0);
    GU_ITER(kk + 1, 1, g0, u0, g1, u1);
  }
#undef GU_ITER
#undef GU_BODY
#undef GU_WAIT_STEADY
#undef GU_XDMA

  // epilogue: SwiGLU + bf16 store (C/D: row=(lane>>4)*4+reg, col=lane&15)
#pragma unroll
  for (int mi = 0; mi < 4; ++mi)
#pragma unroll
    for (int ni = 0; ni < 2; ++ni)
#pragma unroll
      for (int r = 0; r < 4; ++r) {
        int grow = wrM * 64 + mi * 16 + lk * 4 + r;
        int p = mt * BM + grow;
        if (p < ne && grow < vr) {
          int col = ib + wrN * 32 + ni * 16 + lrow;
          float g = accG[mi][ni][r], u = accU[mi][ni][r];
          float hv = g / (1.f + __expf(-g)) * u;
          h_buf[(size_t)(off + p) * I_DIM + col] = f2bf(hv);
        }
      }
}

// ================= stage 2: y += route_w * (h Wd^T) =================
// BM=384, BN=64, BK=32, 768 thr; A (bf16 h) via DMA (all waves),
// B (wd f32) reg-staged by waves 0-7; vmcnt 3/2.
#define DN_NIT 24
#define DN_TILES 96

__global__ __launch_bounds__(768, 6) void gemm_down_kernel(
    const ushort_t* __restrict__ h_buf, const float* __restrict__ wd,
    const int* __restrict__ offsets, const int* __restrict__ counts,
    const int* __restrict__ pair_token, const float* __restrict__ pair_w,
    const int* __restrict__ tile_list, const int* __restrict__ n_tiles,
    float* __restrict__ y) {
  int idx = blockIdx.x;
  int tl = idx >> 4, nt = idx & 15;
  if (tl >= *n_tiles) return;
  int ent = tile_list[tl];
  int e = ent >> 2, mt = ent & 3;
  int ne = counts[e], off = offsets[e];
  int hb = nt * 64;
  int vr = ne - mt * BM;
  if (vr <= 0) return;
  if (vr > BM) vr = BM;

  __shared__ __align__(16) ushort_t Ah[2][BM * 32];  // 24 KB x2
  __shared__ __align__(16) ushort_t Bs[2][64 * 32];  //  4 KB x2
  __shared__ int sTok[BM];
  __shared__ float sPw[BM];

  const int tid = threadIdx.x;
  const int lane = tid & 63;
  const int wid = tid >> 6;
  if (tid < BM) {
    int p = mt * BM + tid;
    int ix = off + (p < ne ? p : ne - 1);
    sTok[tid] = pair_token[ix];
    sPw[tid] = pair_w[ix];
  }
  __syncthreads();

  const ushort_t* asrc[2];
#pragma unroll
  for (int j = 0; j < 2; ++j) {
    int p = j * 768 + tid;
    int row = p >> 2, c = p & 3;
    int pr = mt * BM + row;
    int hr = off + (pr < ne ? pr : ne - 1);
    asrc[j] = h_buf + (size_t)hr * I_DIM + ((c ^ ((row >> 1) & 3)) << 3);
  }
  const float* bsrc = wd;
  int bdsti = 0;
  if (wid < 8) {
    int brow = tid >> 3, bq = tid & 7;
    bsrc = wd + ((size_t)e * H_DIM + hb + brow) * I_DIM + bq * 4;
    bdsti = brow * 32 + (((bq >> 1) ^ ((brow >> 1) & 3)) << 3) + ((bq & 1) << 2);
  }

  const int wrM = wid >> 1, wrN = wid & 1;
  const int lrow = lane & 15, lk = lane >> 4;
  const bool wact = (wrM * 64) < vr;

  f32x4 acc[4][2];
#pragma unroll
  for (int mi = 0; mi < 4; ++mi)
#pragma unroll
    for (int ni = 0; ni < 2; ++ni) acc[mi][ni] = f32x4{0.f, 0.f, 0.f, 0.f};

  f32x4 b0 = {0, 0, 0, 0}, b1 = {0, 0, 0, 0};

#define DN_ADMA(B, K0)                                             \
  do {                                                             \
    async16(&Ah[B][(wid * 64) * 8], asrc[0] + (K0));               \
    async16(&Ah[B][(768 + wid * 64) * 8], asrc[1] + (K0));         \
  } while (0)

#define DN_WAIT_STEADY                                                      \
  do {                                                                      \
    if (wid < 8) asm volatile("s_waitcnt vmcnt(3)" ::: "memory");           \
    else         asm volatile("s_waitcnt vmcnt(2)" ::: "memory");           \
  } while (0)

#define DN_BODY(B)                                                                       \
  do {                                                                                   \
    if (wact) {                                                                          \
      __builtin_amdgcn_s_setprio(1);                                                     \
      bf16x8 af[4];                                                                      \
      _Pragma("unroll") for (int mi = 0; mi < 4; ++mi) {                                 \
        int r = wrM * 64 + mi * 16 + lrow;                                               \
        af[mi] = __builtin_bit_cast(                                                     \
            bf16x8, *(const u16x8*)&Ah[B][r * 32 + ((lk ^ ((r >> 1) & 3)) << 3)]);       \
      }                                                                                  \
      _Pragma("unroll") for (int ni = 0; ni < 2; ++ni) {                                 \
        int br = wrN * 32 + ni * 16 + lrow;                                              \
        bf16x8 bb = __builtin_bit_cast(                                                  \
            bf16x8, *(const u16x8*)&Bs[B][br * 32 + ((lk ^ ((br >> 1) & 3)) << 3)]);     \
        _Pragma("unroll") for (int mi = 0; mi < 4; ++mi)                                 \
            acc[mi][ni] =                                                                \
                __builtin_amdgcn_mfma_f32_16x16x32_bf16(af[mi], bb, acc[mi][ni], 0, 0, 0);\
      }                                                                                  \
      __builtin_amdgcn_s_setprio(0);                                                     \
    }                                                                                    \
  } while (0)

#define DN_ITER(K, B, BW, BI)                                            \
  do {                                                                   \
    if ((K) + 2 < DN_NIT && wid < 8)                                     \
      BI = *(const f32x4*)(bsrc + ((K) + 2) * 32);                       \
    DN_BODY(B);                                                          \
    asm volatile("s_waitcnt lgkmcnt(0)" ::: "memory");                   \
    __builtin_amdgcn_s_barrier();                                        \
    __builtin_amdgcn_sched_barrier(0);                                   \
    if ((K) + 2 < DN_NIT) {                                              \
      DN_ADMA(B, ((K) + 2) * 32);                                        \
      DN_WAIT_STEADY;                                                    \
    } else {                                                             \
      asm volatile("s_waitcnt vmcnt(0)" ::: "memory");                   \
    }                                                                    \
    __builtin_amdgcn_sched_barrier(0);                                   \
    if ((K) + 1 < DN_NIT && wid < 8)                                     \
      *(bf16x4*)&Bs[(B) ^ 1][bdsti] = cvt4b(BW);                         \
    asm volatile("s_waitcnt lgkmcnt(0)" ::: "memory");                   \
    __builtin_amdgcn_s_barrier();                                        \
    __builtin_amdgcn_sched_barrier(0);                                   \
  } while (0)

  if (wid < 8) b0 = *(const f32x4*)(bsrc);
  DN_ADMA(0, 0);
  if (wid < 8) b1 = *(const f32x4*)(bsrc + 32);
  DN_ADMA(1, 32);
  DN_WAIT_STEADY;
  __builtin_amdgcn_sched_barrier(0);
  if (wid < 8) *(bf16x4*)&Bs[0][bdsti] = cvt4b(b0);
  asm volatile("s_waitcnt lgkmcnt(0)" ::: "memory");
  __builtin_amdgcn_s_barrier();
  __builtin_amdgcn_sched_barrier(0);

  for (int kk = 0; kk < DN_NIT; kk += 2) {
    DN_ITER(kk, 0, b1, b0);
    DN_ITER(kk + 1, 1, b0, b1);
  }
#undef DN_ITER
#undef DN_BODY
#undef DN_WAIT_STEADY
#undef DN_ADMA

#pragma unroll
  for (int mi = 0; mi < 4; ++mi)
#pragma unroll
    for (int ni = 0; ni < 2; ++ni)
#pragma unroll
      for (int r = 0; r < 4; ++r) {
        int grow = wrM * 64 + mi * 16 + lk * 4 + r;
        int p = mt * BM + grow;
        if (p < ne && grow < vr) {
          int col = hb + wrN * 32 + ni * 16 + lrow;
          float val = acc[mi][ni][r] * sPw[grow];
          unsafeAtomicAdd(&y[(size_t)sTok[grow] * H_DIM + col], val);
        }
      }
}

extern "C" void kernel_launch(void* const* d_in, const int* in_sizes, int n_in,
                              void* d_out, int out_size, void* d_ws, size_t ws_size,
                              hipStream_t stream) {
  const float* x  = (const float*)d_in[0];
  const float* wr = (const float*)d_in[1];
  const float* wg = (const float*)d_in[2];
  const float* wu = (const float*)d_in[3];
  const float* wd = (const float*)d_in[4];
  float* y = (float*)d_out;

  char* ws = (char*)d_ws;
  int* counts    = (int*)(ws + 0);
  int* offsets   = (int*)(ws + 256);
  int* cursor    = (int*)(ws + 512);
  int* n_tiles   = (int*)(ws + 768);
  int* tile_list = (int*)(ws + 1024);
  int*   topk_id    = (int*)(ws + 2048);
  float* topk_w     = (float*)(ws + 2048 + 1 * 65536);
  int*   pair_token = (int*)(ws + 2048 + 2 * 65536);
  float* pair_w     = (float*)(ws + 2048 + 3 * 65536);
  ushort_t* h_buf = (ushort_t*)(ws + 2048 + 4 * 65536);  // 25.2 MB
  ushort_t* xb = (ushort_t*)(ws + 2048 + 4 * 65536 + (size_t)T_TOK * I_DIM * K_TOP * 2);  // 4 MB

  hipMemsetAsync(counts, 0, 256, stream);
  hipMemsetAsync(y, 0, (size_t)T_TOK * H_DIM * sizeof(float), stream);

  xcast_kernel<<<(T_TOK * H_DIM / 8) / 256, 256, 0, stream>>>(x, xb);
  router_kernel<<<T_TOK, 64, 0, stream>>>(x, wr, topk_id, topk_w, counts);
  scan_kernel<<<1, 64, 0, stream>>>(counts, offsets, cursor, tile_list, n_tiles);
  build_kernel<<<(T_TOK * K_TOP) / 256, 256, 0, stream>>>(topk_id, topk_w, cursor, pair_token, pair_w);
  gemm_gu_kernel<<<GU_TILES * 12, 768, 0, stream>>>(
      xb, wg, wu, offsets, counts, pair_token, tile_list, n_tiles, h_buf);
  gemm_down_kernel<<<DN_TILES * 16, 768, 0, stream>>>(
      h_buf, wd, offsets, counts, pair_token, pair_w, tile_list, n_tiles, y);
}

// Round 7
// 461.958 us; speedup vs baseline: 3.2483x; 3.2483x over previous
//
#include <hip/hip_runtime.h>
#include <hip/hip_bf16.h>
#include <cstdint>
#include <cstddef>

// Qwen3 MoE layer: T=2048 tokens, H=1024 hidden, E=64 experts, I=768, top-K=8
#define T_TOK 2048
#define H_DIM 1024
#define E_NUM 64
#define I_DIM 768
#define K_TOP 8

typedef __attribute__((ext_vector_type(8))) __bf16 bf16x8;
typedef __attribute__((ext_vector_type(4))) __bf16 bf16x4;
typedef __attribute__((ext_vector_type(8))) unsigned short u16x8;
typedef __attribute__((ext_vector_type(4))) float f32x4;
typedef unsigned short ushort_t;

__device__ __forceinline__ unsigned short f2bf(float f) {
  uint32_t u = __builtin_bit_cast(uint32_t, f);
  u += 0x7fffu + ((u >> 16) & 1u);
  return (unsigned short)(u >> 16);
}

__device__ __forceinline__ bf16x8 cvt8b(f32x4 a, f32x4 b) {
  bf16x8 r;
  r[0] = (__bf16)a[0]; r[1] = (__bf16)a[1]; r[2] = (__bf16)a[2]; r[3] = (__bf16)a[3];
  r[4] = (__bf16)b[0]; r[5] = (__bf16)b[1]; r[6] = (__bf16)b[2]; r[7] = (__bf16)b[3];
  return r;
}

__device__ __forceinline__ bf16x4 cvt4b(f32x4 a) {
  bf16x4 r;
  r[0] = (__bf16)a[0]; r[1] = (__bf16)a[1]; r[2] = (__bf16)a[2]; r[3] = (__bf16)a[3];
  return r;
}

// async 16B global -> LDS; dest = wave-uniform base (HW adds lane*16)
__device__ __forceinline__ void async16(const void* l, const void* g) {
  __builtin_amdgcn_global_load_lds(
      (const __attribute__((address_space(1))) unsigned int*)g,
      (__attribute__((address_space(3))) unsigned int*)l, 16, 0, 0);
}

// ---------------- x f32 -> bf16 pre-cast ----------------
__global__ __launch_bounds__(256) void xcast_kernel(const float* __restrict__ x,
                                                    ushort_t* __restrict__ xb) {
  int i = blockIdx.x * 256 + threadIdx.x;
  const f32x4* s = (const f32x4*)(x + (size_t)i * 8);
  *(bf16x8*)(xb + (size_t)i * 8) = cvt8b(s[0], s[1]);
}

// ---------------- router ----------------
__global__ __launch_bounds__(64) void router_kernel(
    const float* __restrict__ x, const float* __restrict__ wr,
    int* __restrict__ topk_id, float* __restrict__ topk_w,
    int* __restrict__ counts) {
  const int t = blockIdx.x;
  const int e = threadIdx.x;
  const float4* xv = (const float4*)(x + (size_t)t * H_DIM);
  const float4* wv = (const float4*)(wr + (size_t)e * H_DIM);
  float acc = 0.f;
#pragma unroll 8
  for (int i = 0; i < H_DIM / 4; ++i) {
    float4 a = xv[i], b = wv[i];
    acc = fmaf(a.x, b.x, acc);
    acc = fmaf(a.y, b.y, acc);
    acc = fmaf(a.z, b.z, acc);
    acc = fmaf(a.w, b.w, acc);
  }
  float m = acc;
  for (int o = 32; o; o >>= 1) m = fmaxf(m, __shfl_xor(m, o));
  float p = __expf(acc - m);
  float s = p;
  for (int o = 32; o; o >>= 1) s += __shfl_xor(s, o);
  p /= s;
  float v = p;
  int sid = 0;
  float sw = 0.f;
  for (int k = 0; k < K_TOP; ++k) {
    float bv = v;
    int bi = e;
    for (int o = 32; o; o >>= 1) {
      float ov = __shfl_xor(bv, o);
      int oi = __shfl_xor(bi, o);
      if (ov > bv || (ov == bv && oi < bi)) { bv = ov; bi = oi; }
    }
    if (e == k) { sid = bi; sw = bv; }
    if (e == bi) v = -1.f;
  }
  float ssum = (e < K_TOP) ? sw : 0.f;
  for (int o = 32; o; o >>= 1) ssum += __shfl_xor(ssum, o);
  if (e < K_TOP) {
    topk_id[t * K_TOP + e] = sid;
    topk_w[t * K_TOP + e] = sw / ssum;
    atomicAdd(&counts[sid], 1);
  }
}

// ---------------- scan + packed tile list (BM=256, max 2 tiles/expert) ----------------
__global__ void scan_kernel(const int* __restrict__ counts,
                            int* __restrict__ offsets, int* __restrict__ cursor,
                            int* __restrict__ tile_list, int* __restrict__ n_tiles) {
  if (threadIdx.x == 0) {
    int a = 0, n = 0;
    for (int e = 0; e < E_NUM; ++e) {
      offsets[e] = a;
      cursor[e] = a;
      int ne = counts[e];
      a += ne;
      int tl = (ne + 255) >> 8;
      if (tl > 2) tl = 2;
      for (int m = 0; m < tl; ++m) tile_list[n++] = (e << 2) | m;
    }
    *n_tiles = n;
  }
}

__global__ __launch_bounds__(256) void build_kernel(
    const int* __restrict__ topk_id, const float* __restrict__ topk_w,
    int* __restrict__ cursor, int* __restrict__ pair_token, float* __restrict__ pair_w) {
  int i = blockIdx.x * 256 + threadIdx.x;
  int t = i >> 3;
  int e = topk_id[i];
  int pos = atomicAdd(&cursor[e], 1);
  pair_token[pos] = t;
  pair_w[pos] = topk_w[i];
}

// bf16 LDS rows of 32 bf16 (64 B = 4 chunks of 16 B); chunk slot = c ^ ((row>>1)&3)

// ================= stage 1: h = silu(X Wg^T) * (X Wu^T) =================
// BM=256, BN=64 (G and U), BK=32, 512 thr (8 waves 4Mx2N), 2 blocks/CU.
// X: depth-3 global_load_lds (3 LDS bufs). W: reg-staged f32->bf16, depth-2.
// Steady vmcnt(6) = {X(it+2),W(it+2),X(it+3)} in flight; never drained mid-loop.
#define GU_NIT 32

__global__ __launch_bounds__(512, 4) void gemm_gu_kernel(
    const ushort_t* __restrict__ xb, const float* __restrict__ wg,
    const float* __restrict__ wu, const int* __restrict__ offsets,
    const int* __restrict__ counts, const int* __restrict__ pair_token,
    const int* __restrict__ tile_list, const int* __restrict__ n_tiles,
    ushort_t* __restrict__ h_buf) {
  int idx = blockIdx.x;  // natural order: dead tail round-robins across XCDs
  int tl = idx / 12, nt = idx - tl * 12;
  if (tl >= *n_tiles) return;
  int ent = tile_list[tl];
  int e = ent >> 2, mt = ent & 3;
  int ne = counts[e], off = offsets[e];
  int ib = nt * 64;
  int vr = ne - mt * 256;
  if (vr <= 0) return;
  if (vr > 256) vr = 256;

  __shared__ __align__(16) ushort_t Xs[3][256 * 32];  // 16 KB x3
  __shared__ __align__(16) ushort_t Gs[2][64 * 32];   //  4 KB x2
  __shared__ __align__(16) ushort_t Us[2][64 * 32];   //  4 KB x2
  __shared__ int sTok[256];

  const int tid = threadIdx.x;
  const int lane = tid & 63;
  const int wid = tid >> 6;  // 0..7
  if (tid < 256) {
    int p = mt * 256 + tid;
    sTok[tid] = pair_token[off + (p < ne ? p : ne - 1)];
  }
  __syncthreads();

  // X DMA: 1024 chunks of 16B, 2/thread; linear LDS dest + inverse-swizzled src
  const ushort_t* xsrc[2];
#pragma unroll
  for (int j = 0; j < 2; ++j) {
    int p = j * 512 + tid;
    int row = p >> 2, c = p & 3;
    xsrc[j] = xb + (size_t)sTok[row] * H_DIM + ((c ^ ((row >> 1) & 3)) << 3);
  }
  // W reg-staging: 1 f32x4 per mat per iter; swizzled bf16x4 ds_write dest
  const int wrow = tid >> 3, wq = tid & 7;
  const float* gsrc = wg + ((size_t)e * I_DIM + ib + wrow) * H_DIM + wq * 4;
  const float* usrc = wu + ((size_t)e * I_DIM + ib + wrow) * H_DIM + wq * 4;
  const int wdsti = wrow * 32 + (((wq >> 1) ^ ((wrow >> 1) & 3)) << 3) + ((wq & 1) << 2);

  const int wrM = wid >> 1, wrN = wid & 1;
  const int lrow = lane & 15, lk = lane >> 4;
  const bool wact = (wrM * 64) < vr;

  f32x4 accG[4][2], accU[4][2];
#pragma unroll
  for (int mi = 0; mi < 4; ++mi)
#pragma unroll
    for (int ni = 0; ni < 2; ++ni) {
      accG[mi][ni] = f32x4{0.f, 0.f, 0.f, 0.f};
      accU[mi][ni] = f32x4{0.f, 0.f, 0.f, 0.f};
    }

  f32x4 g0, u0, g1, u1;

#define GU_XDMA(XB, K0)                                            \
  do {                                                             \
    async16(&Xs[XB][(wid * 64) * 8], xsrc[0] + (K0));              \
    async16(&Xs[XB][(512 + wid * 64) * 8], xsrc[1] + (K0));        \
  } while (0)

#define GU_BODY(XB, WB)                                                                  \
  do {                                                                                   \
    if (wact) {                                                                          \
      __builtin_amdgcn_s_setprio(1);                                                     \
      bf16x8 af[4];                                                                      \
      _Pragma("unroll") for (int mi = 0; mi < 4; ++mi) {                                 \
        int r = wrM * 64 + mi * 16 + lrow;                                               \
        af[mi] = __builtin_bit_cast(                                                     \
            bf16x8, *(const u16x8*)&Xs[XB][r * 32 + ((lk ^ ((r >> 1) & 3)) << 3)]);      \
      }                                                                                  \
      _Pragma("unroll") for (int ni = 0; ni < 2; ++ni) {                                 \
        int br = wrN * 32 + ni * 16 + lrow;                                              \
        int ci = br * 32 + ((lk ^ ((br >> 1) & 3)) << 3);                                \
        bf16x8 bg = __builtin_bit_cast(bf16x8, *(const u16x8*)&Gs[WB][ci]);              \
        bf16x8 bu = __builtin_bit_cast(bf16x8, *(const u16x8*)&Us[WB][ci]);              \
        _Pragma("unroll") for (int mi = 0; mi < 4; ++mi) {                               \
          accG[mi][ni] =                                                                 \
              __builtin_amdgcn_mfma_f32_16x16x32_bf16(af[mi], bg, accG[mi][ni], 0, 0, 0);\
          accU[mi][ni] =                                                                 \
              __builtin_amdgcn_mfma_f32_16x16x32_bf16(af[mi], bu, accU[mi][ni], 0, 0, 0);\
        }                                                                                \
      }                                                                                  \
      __builtin_amdgcn_s_setprio(0);                                                     \
    }                                                                                    \
  } while (0)

// iter K with X buf XB (=K%3), W buf WB (=K&1): load W(K+2) into (GL,UL); compute;
// bar#1 (Xs[K%3] reads done); XDMA(K+3) -> same buf; vmcnt(6) -> X(K+1),W(K+1) landed;
// ds_write W(K+1) from (GH,UH) -> buf WB^1; bar#2.
#define GU_ITER(K, XB, GH, UH, GL, UL)                                   \
  do {                                                                   \
    {                                                                    \
      int kw = ((K) + 2 < GU_NIT) ? ((K) + 2) * 32 : 0;                  \
      GL = *(const f32x4*)(gsrc + kw);                                   \
      UL = *(const f32x4*)(usrc + kw);                                   \
    }                                                                    \
    GU_BODY(XB, (K) & 1);                                                \
    __builtin_amdgcn_s_barrier();                                        \
    __builtin_amdgcn_sched_barrier(0);                                   \
    {                                                                    \
      int kx = ((K) + 3 < GU_NIT) ? ((K) + 3) * 32 : 0;                  \
      GU_XDMA(XB, kx);                                                   \
    }                                                                    \
    asm volatile("s_waitcnt vmcnt(6)" ::: "memory");                     \
    __builtin_amdgcn_sched_barrier(0);                                   \
    *(bf16x4*)&Gs[((K) + 1) & 1][wdsti] = cvt4b(GH);                     \
    *(bf16x4*)&Us[((K) + 1) & 1][wdsti] = cvt4b(UH);                     \
    asm volatile("s_waitcnt lgkmcnt(0)" ::: "memory");                   \
    __builtin_amdgcn_s_barrier();                                        \
    __builtin_amdgcn_sched_barrier(0);                                   \
  } while (0)

  // prologue FIFO: [X0(2), g0,u0, X1(2), g1,u1, X2(2)] -> vmcnt(6): X0,W0 done
  GU_XDMA(0, 0);
  g0 = *(const f32x4*)(gsrc);
  u0 = *(const f32x4*)(usrc);
  GU_XDMA(1, 32);
  g1 = *(const f32x4*)(gsrc + 32);
  u1 = *(const f32x4*)(usrc + 32);
  GU_XDMA(2, 64);
  asm volatile("s_waitcnt vmcnt(6)" ::: "memory");
  __builtin_amdgcn_sched_barrier(0);
  *(bf16x4*)&Gs[0][wdsti] = cvt4b(g0);
  *(bf16x4*)&Us[0][wdsti] = cvt4b(u0);
  asm volatile("s_waitcnt lgkmcnt(0)" ::: "memory");
  __builtin_amdgcn_s_barrier();
  __builtin_amdgcn_sched_barrier(0);

  // 32 iters: unroll 6 (x-buf period 3 x w-buf period 2), then 2 tail iters
  int kk = 0;
#pragma unroll 1
  for (; kk + 6 <= GU_NIT; kk += 6) {
    GU_ITER(kk + 0, 0, g1, u1, g0, u0);
    GU_ITER(kk + 1, 1, g0, u0, g1, u1);
    GU_ITER(kk + 2, 2, g1, u1, g0, u0);
    GU_ITER(kk + 3, 0, g0, u0, g1, u1);
    GU_ITER(kk + 4, 1, g1, u1, g0, u0);
    GU_ITER(kk + 5, 2, g0, u0, g1, u1);
  }
  GU_ITER(30, 0, g1, u1, g0, u0);
  GU_ITER(31, 1, g0, u0, g1, u1);
  asm volatile("s_waitcnt vmcnt(0)" ::: "memory");
#undef GU_ITER
#undef GU_BODY
#undef GU_XDMA

  // epilogue: SwiGLU + bf16 store (C/D: row=(lane>>4)*4+reg, col=lane&15)
#pragma unroll
  for (int mi = 0; mi < 4; ++mi)
#pragma unroll
    for (int ni = 0; ni < 2; ++ni)
#pragma unroll
      for (int r = 0; r < 4; ++r) {
        int grow = wrM * 64 + mi * 16 + lk * 4 + r;
        int p = mt * 256 + grow;
        if (p < ne && grow < vr) {
          int col = ib + wrN * 32 + ni * 16 + lrow;
          float g = accG[mi][ni][r], u = accU[mi][ni][r];
          float hv = g / (1.f + __expf(-g)) * u;
          h_buf[(size_t)(off + p) * I_DIM + col] = f2bf(hv);
        }
      }
}

// ================= stage 2: y += route_w * (h Wd^T) =================
// BM=256, BN=128, BK=32, 512 thr (8 waves 4Mx2N); A depth-3 DMA, B reg-staged.
#define DN_NIT 24

__global__ __launch_bounds__(512, 4) void gemm_down_kernel(
    const ushort_t* __restrict__ h_buf, const float* __restrict__ wd,
    const int* __restrict__ offsets, const int* __restrict__ counts,
    const int* __restrict__ pair_token, const float* __restrict__ pair_w,
    const int* __restrict__ tile_list, const int* __restrict__ n_tiles,
    float* __restrict__ y) {
  int idx = blockIdx.x;
  int tl = idx >> 3, nt = idx & 7;
  if (tl >= *n_tiles) return;
  int ent = tile_list[tl];
  int e = ent >> 2, mt = ent & 3;
  int ne = counts[e], off = offsets[e];
  int hb = nt * 128;
  int vr = ne - mt * 256;
  if (vr <= 0) return;
  if (vr > 256) vr = 256;

  __shared__ __align__(16) ushort_t Ah[3][256 * 32];  // 16 KB x3
  __shared__ __align__(16) ushort_t Bs[2][128 * 32];  //  8 KB x2
  __shared__ int sTok[256];
  __shared__ float sPw[256];

  const int tid = threadIdx.x;
  const int lane = tid & 63;
  const int wid = tid >> 6;
  if (tid < 256) {
    int p = mt * 256 + tid;
    int ix = off + (p < ne ? p : ne - 1);
    sTok[tid] = pair_token[ix];
    sPw[tid] = pair_w[ix];
  }
  __syncthreads();

  const ushort_t* asrc[2];
#pragma unroll
  for (int j = 0; j < 2; ++j) {
    int p = j * 512 + tid;
    int row = p >> 2, c = p & 3;
    int pr = mt * 256 + row;
    int hr = off + (pr < ne ? pr : ne - 1);
    asrc[j] = h_buf + (size_t)hr * I_DIM + ((c ^ ((row >> 1) & 3)) << 3);
  }
  // B: 128 rows x 32 k f32 = 16 KB/iter -> 2 f32x4 loads + 2 bf16x4 writes per thread
  const float* bsrc[2];
  int bdsti[2];
#pragma unroll
  for (int j = 0; j < 2; ++j) {
    int p = j * 512 + tid;
    int row = p >> 3, q = p & 7;
    bsrc[j] = wd + ((size_t)e * H_DIM + hb + row) * I_DIM + q * 4;
    bdsti[j] = row * 32 + (((q >> 1) ^ ((row >> 1) & 3)) << 3) + ((q & 1) << 2);
  }

  const int wrM = wid >> 1, wrN = wid & 1;
  const int lrow = lane & 15, lk = lane >> 4;
  const bool wact = (wrM * 64) < vr;

  f32x4 acc[4][4];
#pragma unroll
  for (int mi = 0; mi < 4; ++mi)
#pragma unroll
    for (int ni = 0; ni < 4; ++ni) acc[mi][ni] = f32x4{0.f, 0.f, 0.f, 0.f};

  f32x4 b0a, b0b, b1a, b1b;

#define DN_ADMA(XB, K0)                                            \
  do {                                                             \
    async16(&Ah[XB][(wid * 64) * 8], asrc[0] + (K0));              \
    async16(&Ah[XB][(512 + wid * 64) * 8], asrc[1] + (K0));        \
  } while (0)

#define DN_BODY(XB, WB)                                                                  \
  do {                                                                                   \
    if (wact) {                                                                          \
      __builtin_amdgcn_s_setprio(1);                                                     \
      bf16x8 af[4];                                                                      \
      _Pragma("unroll") for (int mi = 0; mi < 4; ++mi) {                                 \
        int r = wrM * 64 + mi * 16 + lrow;                                               \
        af[mi] = __builtin_bit_cast(                                                     \
            bf16x8, *(const u16x8*)&Ah[XB][r * 32 + ((lk ^ ((r >> 1) & 3)) << 3)]);      \
      }                                                                                  \
      _Pragma("unroll") for (int ni = 0; ni < 4; ++ni) {                                 \
        int br = wrN * 64 + ni * 16 + lrow;                                              \
        bf16x8 bb = __builtin_bit_cast(                                                  \
            bf16x8, *(const u16x8*)&Bs[WB][br * 32 + ((lk ^ ((br >> 1) & 3)) << 3)]);    \
        _Pragma("unroll") for (int mi = 0; mi < 4; ++mi)                                 \
            acc[mi][ni] =                                                                \
                __builtin_amdgcn_mfma_f32_16x16x32_bf16(af[mi], bb, acc[mi][ni], 0, 0, 0);\
      }                                                                                  \
      __builtin_amdgcn_s_setprio(0);                                                     \
    }                                                                                    \
  } while (0)

#define DN_ITER(K, XB, BHa, BHb, BLa, BLb)                               \
  do {                                                                   \
    {                                                                    \
      int kw = ((K) + 2 < DN_NIT) ? ((K) + 2) * 32 : 0;                  \
      BLa = *(const f32x4*)(bsrc[0] + kw);                               \
      BLb = *(const f32x4*)(bsrc[1] + kw);                               \
    }                                                                    \
    DN_BODY(XB, (K) & 1);                                                \
    __builtin_amdgcn_s_barrier();                                        \
    __builtin_amdgcn_sched_barrier(0);                                   \
    {                                                                    \
      int kx = ((K) + 3 < DN_NIT) ? ((K) + 3) * 32 : 0;                  \
      DN_ADMA(XB, kx);                                                   \
    }                                                                    \
    asm volatile("s_waitcnt vmcnt(6)" ::: "memory");                     \
    __builtin_amdgcn_sched_barrier(0);                                   \
    *(bf16x4*)&Bs[((K) + 1) & 1][bdsti[0]] = cvt4b(BHa);                 \
    *(bf16x4*)&Bs[((K) + 1) & 1][bdsti[1]] = cvt4b(BHb);                 \
    asm volatile("s_waitcnt lgkmcnt(0)" ::: "memory");                   \
    __builtin_amdgcn_s_barrier();                                        \
    __builtin_amdgcn_sched_barrier(0);                                   \
  } while (0)

  DN_ADMA(0, 0);
  b0a = *(const f32x4*)(bsrc[0]);
  b0b = *(const f32x4*)(bsrc[1]);
  DN_ADMA(1, 32);
  b1a = *(const f32x4*)(bsrc[0] + 32);
  b1b = *(const f32x4*)(bsrc[1] + 32);
  DN_ADMA(2, 64);
  asm volatile("s_waitcnt vmcnt(6)" ::: "memory");
  __builtin_amdgcn_sched_barrier(0);
  *(bf16x4*)&Bs[0][bdsti[0]] = cvt4b(b0a);
  *(bf16x4*)&Bs[0][bdsti[1]] = cvt4b(b0b);
  asm volatile("s_waitcnt lgkmcnt(0)" ::: "memory");
  __builtin_amdgcn_s_barrier();
  __builtin_amdgcn_sched_barrier(0);

  int kk = 0;
#pragma unroll 1
  for (; kk + 6 <= DN_NIT; kk += 6) {
    DN_ITER(kk + 0, 0, b1a, b1b, b0a, b0b);
    DN_ITER(kk + 1, 1, b0a, b0b, b1a, b1b);
    DN_ITER(kk + 2, 2, b1a, b1b, b0a, b0b);
    DN_ITER(kk + 3, 0, b0a, b0b, b1a, b1b);
    DN_ITER(kk + 4, 1, b1a, b1b, b0a, b0b);
    DN_ITER(kk + 5, 2, b0a, b0b, b1a, b1b);
  }
  asm volatile("s_waitcnt vmcnt(0)" ::: "memory");
#undef DN_ITER
#undef DN_BODY
#undef DN_ADMA

#pragma unroll
  for (int mi = 0; mi < 4; ++mi)
#pragma unroll
    for (int ni = 0; ni < 4; ++ni)
#pragma unroll
      for (int r = 0; r < 4; ++r) {
        int grow = wrM * 64 + mi * 16 + lk * 4 + r;
        int p = mt * 256 + grow;
        if (p < ne && grow < vr) {
          int col = hb + wrN * 64 + ni * 16 + lrow;
          float val = acc[mi][ni][r] * sPw[grow];
          unsafeAtomicAdd(&y[(size_t)sTok[grow] * H_DIM + col], val);
        }
      }
}

extern "C" void kernel_launch(void* const* d_in, const int* in_sizes, int n_in,
                              void* d_out, int out_size, void* d_ws, size_t ws_size,
                              hipStream_t stream) {
  const float* x  = (const float*)d_in[0];
  const float* wr = (const float*)d_in[1];
  const float* wg = (const float*)d_in[2];
  const float* wu = (const float*)d_in[3];
  const float* wd = (const float*)d_in[4];
  float* y = (float*)d_out;

  char* ws = (char*)d_ws;
  int* counts    = (int*)(ws + 0);
  int* offsets   = (int*)(ws + 256);
  int* cursor    = (int*)(ws + 512);
  int* n_tiles   = (int*)(ws + 768);
  int* tile_list = (int*)(ws + 1024);
  int*   topk_id    = (int*)(ws + 2048);
  float* topk_w     = (float*)(ws + 2048 + 1 * 65536);
  int*   pair_token = (int*)(ws + 2048 + 2 * 65536);
  float* pair_w     = (float*)(ws + 2048 + 3 * 65536);
  ushort_t* h_buf = (ushort_t*)(ws + 2048 + 4 * 65536);  // 25.2 MB
  ushort_t* xb = (ushort_t*)(ws + 2048 + 4 * 65536 + (size_t)T_TOK * I_DIM * K_TOP * 2);  // 4 MB

  hipMemsetAsync(counts, 0, 256, stream);
  hipMemsetAsync(y, 0, (size_t)T_TOK * H_DIM * sizeof(float), stream);

  xcast_kernel<<<(T_TOK * H_DIM / 8) / 256, 256, 0, stream>>>(x, xb);
  router_kernel<<<T_TOK, 64, 0, stream>>>(x, wr, topk_id, topk_w, counts);
  scan_kernel<<<1, 64, 0, stream>>>(counts, offsets, cursor, tile_list, n_tiles);
  build_kernel<<<(T_TOK * K_TOP) / 256, 256, 0, stream>>>(topk_id, topk_w, cursor, pair_token, pair_w);
  gemm_gu_kernel<<<128 * 12, 512, 0, stream>>>(
      xb, wg, wu, offsets, counts, pair_token, tile_list, n_tiles, h_buf);
  gemm_down_kernel<<<128 * 8, 512, 0, stream>>>(
      h_buf, wd, offsets, counts, pair_token, pair_w, tile_list, n_tiles, y);
}